// Round 1
// baseline (538.914 us; speedup 1.0000x reference)
//
#include <hip/hip_runtime.h>

// Problem constants (fixed by reference setup_inputs)
#define B   64
#define C   256
#define H   64
#define W   64
#define HW  (H * W)
#define KPT 21

// Kernel A: channel mean for both tensors.
// grid = dim3(256, 2): x = b*4 + chunk (4 chunks of 1024 pixels per batch), y = tensor select.
// 256 threads, each handles 4 consecutive pixels via float4 -> fully coalesced,
// loop over 256 channels with stride HW. Reads 512 MB total -> HBM-bound.
__global__ __launch_bounds__(256) void channel_mean_kernel(
    const float* __restrict__ f1, const float* __restrict__ f2,
    float* __restrict__ fm)
{
    const float* f  = blockIdx.y ? f2 : f1;
    float* out      = fm + (size_t)blockIdx.y * B * HW;

    const int b     = blockIdx.x >> 2;                      // batch
    const int pix0  = ((blockIdx.x & 3) * 256 + threadIdx.x) * 4;  // pixel offset in [0,4096)
    const float* base = f + (size_t)b * C * HW + pix0;

    float4 acc = make_float4(0.f, 0.f, 0.f, 0.f);
    #pragma unroll 8
    for (int c = 0; c < C; ++c) {
        const float4 v = *(const float4*)(base + (size_t)c * HW);
        acc.x += v.x; acc.y += v.y; acc.z += v.z; acc.w += v.w;
    }
    const float inv = 1.0f / (float)C;
    float4 o = make_float4(acc.x * inv, acc.y * inv, acc.z * inv, acc.w * inv);
    *(float4*)(out + (size_t)b * HW + pix0) = o;
}

// Kernel B: per-keypoint box means + batch mean.
// grid = 21 blocks (one per keypoint), 128 threads: wave 0 -> f1/pre1, wave 1 -> f2/pre2.
// lane = batch index (B == 64 == wavefront). Each lane sums its clamped box from fm
// (L2-resident, 2 MB), computes box mean, then 64-lane shuffle reduction -> batch mean.
__global__ __launch_bounds__(128) void box_mean_kernel(
    const float* __restrict__ fm,
    const int* __restrict__ pre1, const int* __restrict__ pre2,
    float* __restrict__ feas)   // feas[0..20] = fea_c1, feas[21..41] = fea_c2 (pre-momentum)
{
    const int k    = blockIdx.x;
    const int lane = threadIdx.x & 63;
    const int wave = threadIdx.x >> 6;
    const int b    = lane;

    const int* pre = wave ? pre2 : pre1;
    const float* base = fm + (size_t)wave * B * HW + (size_t)b * HW;

    const int x = pre[(b * KPT + k) * 2 + 0];
    const int y = pre[(b * KPT + k) * 2 + 1];
    // torch slicing: rows from x bounds, cols from y bounds, exclusive upper.
    const int l = max(x - 6, 0);
    const int r = min(x + 6, 63);
    const int d = max(y - 6, 0);
    const int u = min(y + 6, 63);

    float s = 0.f;
    for (int row = l; row < r; ++row) {
        const float* rp = base + row * W;
        for (int col = d; col < u; ++col)
            s += rp[col];
    }
    float mean = s / (float)((r - l) * (u - d));

    // wave(64)-wide reduction: sum of box means over batch
    #pragma unroll
    for (int off = 32; off > 0; off >>= 1)
        mean += __shfl_down(mean, off, 64);

    if (lane == 0)
        feas[wave * KPT + k] = mean * (1.0f / (float)B);
}

// Kernel C: final MSE over 21 keypoints with momentum on fea_c2.
__global__ __launch_bounds__(64) void final_mse_kernel(
    const float* __restrict__ feas, float* __restrict__ out)
{
    const int k = threadIdx.x;
    float v = 0.f;
    if (k < KPT) {
        const float diff = feas[k] - 0.999f * feas[KPT + k];
        v = diff * diff;
    }
    #pragma unroll
    for (int off = 32; off > 0; off >>= 1)
        v += __shfl_down(v, off, 64);
    if (threadIdx.x == 0)
        out[0] = v * (1.0f / (float)KPT);
}

extern "C" void kernel_launch(void* const* d_in, const int* in_sizes, int n_in,
                              void* d_out, int out_size, void* d_ws, size_t ws_size,
                              hipStream_t stream)
{
    const float* f1  = (const float*)d_in[0];
    const float* f2  = (const float*)d_in[1];
    const int*  pre1 = (const int*)d_in[2];
    const int*  pre2 = (const int*)d_in[3];

    float* fm   = (float*)d_ws;            // 2 * 64 * 4096 floats = 2 MB
    float* feas = fm + 2 * B * HW;         // 42 floats

    channel_mean_kernel<<<dim3(B * 4, 2), 256, 0, stream>>>(f1, f2, fm);
    box_mean_kernel<<<KPT, 128, 0, stream>>>(fm, pre1, pre2, feas);
    final_mse_kernel<<<1, 64, 0, stream>>>(feas, (float*)d_out);
}